// Round 1
// baseline (295.302 us; speedup 1.0000x reference)
//
#include <hip/hip_runtime.h>
#include <hip/hip_bf16.h>
#include <stdint.h>

// Problem constants
#define B_    16
#define N_    577
#define C_    768
#define H_    12
#define M_    (B_*N_)     // 9232 rows
#define QKVN  (3*C_)      // 2304
#define NKEEP 403         // int(576*0.7)
#define KROWS (NKEEP+1)   // 404
#define VTLD  640         // vtbuf padded row length
#define PTLD  72          // Ptt row stride (ushorts)

typedef short s16x8 __attribute__((ext_vector_type(8)));
typedef float f32x4 __attribute__((ext_vector_type(4)));

__device__ __forceinline__ unsigned short f2bf(float x){
  unsigned int u = __float_as_uint(x);
  u += 0x7FFF + ((u >> 16) & 1);          // round-to-nearest-even
  return (unsigned short)(u >> 16);
}

// async global->LDS, 16B per lane; lds dest = wave-uniform base + lane*16
__device__ __forceinline__ void gld_lds16(const void* g, void* l){
  __builtin_amdgcn_global_load_lds(
      (const __attribute__((address_space(1))) unsigned int*)g,
      (__attribute__((address_space(3))) unsigned int*)l, 16, 0, 0);
}

// Generic XCD-panel tile mapping (used by k_gemm_bt64)
template<int NT, int M9, int MTILES>
__device__ __forceinline__ void tile_map(int L, int& mt, int& nt){
  constexpr int NB = MTILES*NT;
  int x = L & 7, j = L >> 3;
  if(j < M9*NT){
    nt = j/M9; mt = x*M9 + (j - nt*M9);    // n-outer: M9 consecutive blocks share B-tile
  } else {
    int offt = 0;
    #pragma unroll
    for(int y=0;y<8;y++) if(y<x) offt += ((NB-1-y)>>3) + 1 - M9*NT;  // tail_y
    int ft = offt + (j - M9*NT);
    mt = 8*M9 + ft/NT;
    nt = ft - (ft/NT)*NT;
  }
}

// ---------------- cast x -> bf16 (vectorized) ----------------
__global__ void k_cvt_x(const float* __restrict__ x, unsigned short* __restrict__ xb){
  int i = blockIdx.x*256 + threadIdx.x;
  float4 v = ((const float4*)x)[i];
  ushort4 o; o.x=f2bf(v.x); o.y=f2bf(v.y); o.z=f2bf(v.z); o.w=f2bf(v.w);
  ((ushort4*)xb)[i] = o;
}

// ------------- transpose+cast weights: out[c][r] = bf16(in[r][c]) -------------
__global__ void k_transpose_cvt(const float* __restrict__ in, unsigned short* __restrict__ out,
                                int R, int CC){
  __shared__ float tile[64][65];
  int r0 = blockIdx.y*64, c0 = blockIdx.x*64;
  int tx = threadIdx.x & 63, ty = threadIdx.x >> 6;
  #pragma unroll
  for(int i=0;i<16;i++){
    int r = ty + i*4;
    tile[r][tx] = in[(size_t)(r0+r)*CC + c0 + tx];
  }
  __syncthreads();
  #pragma unroll
  for(int i=0;i<16;i++){
    int c = ty + i*4;
    out[(size_t)(c0+c)*R + r0 + tx] = f2bf(tile[tx][c]);
  }
}

// =================================================================================
// QKV GEMM: 256x256 tile, BK=64, 8 waves (2Mx4N), 8-phase counted-vmcnt schedule
// (T2 swizzle + T3/T4 counted vmcnt + T5 setprio). LDS = 8 units of 16KB:
//   unit (h*2|s)   : A half h (128 rows x 64 k), k-tile parity s
//   unit 4+(h*2|s) : B half h (128 cols x 64 k), k-tile parity s
// Swizzle: element (row,kc) stored at byte row*128 + (kc*2 ^ ((row&4)<<3)); LDS
// linear for global_load_lds, source column pre-XORed, ds_read applies same XOR.
// Stage ledger (group g computes k-tile g, slot s=g&1):
//   P1: read A-mh0(8) + B-all(8); stage A-h1(g+1)->s^1
//   P2: stage B-h0(g+2)->s
//   P3: read A-mh1(8);           stage B-h1(g+2)->s
//   P4: stage A-h0(g+2)->s; s_waitcnt vmcnt(6)   (3 half-tiles = 6 loads in flight)
// Each phase: [reads][stage] barrier; lgkmcnt(0)+sched_barrier; 16 MFMA; barrier.
// Tail: g=10 stages only P1 and uses vmcnt(0); g=11 stages nothing.
// V-tiles (n0>=1536) written transposed into vtbuf (FUSEV), rest bf16 into qkvb.
// =================================================================================
__global__ __launch_bounds__(512,2) void k_gemm_qkv(const unsigned short* __restrict__ A,
                          const unsigned short* __restrict__ Bt,
                          unsigned short* __restrict__ qkvb,
                          unsigned short* __restrict__ vtbuf){
  __shared__ __align__(16) unsigned short L[8][8192];   // 128 KiB
  const int t = threadIdx.x;
  const int w = t>>6, l = t&63, lq = l>>4, lr = l&15;
  const int wm = w>>2, wn = w&3;

  // block mapping: bijective XCD swizzle (333 = 8*41+5), m-outer (A-panel sharing)
  int orig = blockIdx.x;
  int xid = orig & 7, j = orig >> 3;
  int wgid = (xid < 5 ? xid*42 : 210 + (xid-5)*41) + j;
  int mt = wgid/9, nt = wgid - mt*9;
  const int m0 = mt*256, n0 = nt*256;

  // staging: lane covers row band w*8+(l>>3), 16B chunk (l&7); source pre-swizzled
  const int rr = w*8 + (l>>3);
  const int csw = ((l&7)*8) ^ ((l&32)?16:0);   // ushort col offset, XOR16 iff row&4
  int ra0 = m0 + rr;        if(ra0 >= M_) ra0 = M_-1;
  int ra1 = m0 + 64 + rr;   if(ra1 >= M_) ra1 = M_-1;
  int ra2 = m0 + 128 + rr;  if(ra2 >= M_) ra2 = M_-1;
  int ra3 = m0 + 192 + rr;  if(ra3 >= M_) ra3 = M_-1;
  const unsigned short* pA00 = A + (size_t)ra0*768 + csw;  // h0 c0
  const unsigned short* pA01 = A + (size_t)ra1*768 + csw;  // h0 c1
  const unsigned short* pA10 = A + (size_t)ra2*768 + csw;  // h1 c0
  const unsigned short* pA11 = A + (size_t)ra3*768 + csw;  // h1 c1
  const unsigned short* pB00 = Bt + (size_t)(n0 + rr)*768 + csw;
  const unsigned short* pB01 = Bt + (size_t)(n0 + 64 + rr)*768 + csw;
  const unsigned short* pB10 = Bt + (size_t)(n0 + 128 + rr)*768 + csw;
  const unsigned short* pB11 = Bt + (size_t)(n0 + 192 + rr)*768 + csw;

#define STAGE_A(H, KT, SLT) do{ \
  unsigned short* d_ = &L[((H)<<1)|(SLT)][(w*8)<<6]; \
  gld_lds16(pA##H##0 + (size_t)(KT)*64, d_); \
  gld_lds16(pA##H##1 + (size_t)(KT)*64, d_ + 4096); \
}while(0)
#define STAGE_B(H, KT, SLT) do{ \
  unsigned short* d_ = &L[4 + (((H)<<1)|(SLT))][(w*8)<<6]; \
  gld_lds16(pB##H##0 + (size_t)(KT)*64, d_); \
  gld_lds16(pB##H##1 + (size_t)(KT)*64, d_ + 4096); \
}while(0)
#define READ_A(MH) do{ \
  _Pragma("unroll") \
  for(int mf=0; mf<4; mf++){ \
    const int R_ = (MH)*64 + mf*16 + lr; \
    const int rx_ = (R_&4)<<2; \
    af[mf][0] = *(const s16x8*)&baseA[R_*64 + ((lq*8) ^ rx_)]; \
    af[mf][1] = *(const s16x8*)&baseA[R_*64 + ((32 + lq*8) ^ rx_)]; \
  } \
}while(0)
#define READ_B() do{ \
  _Pragma("unroll") \
  for(int nf=0; nf<4; nf++){ \
    const int R_ = (wn&1)*64 + nf*16 + lr; \
    const int rx_ = (R_&4)<<2; \
    bf[nf][0] = *(const s16x8*)&baseB[R_*64 + ((lq*8) ^ rx_)]; \
    bf[nf][1] = *(const s16x8*)&baseB[R_*64 + ((32 + lq*8) ^ rx_)]; \
  } \
}while(0)
#define MMA_Q(MH, NH) do{ \
  __builtin_amdgcn_s_setprio(1); \
  _Pragma("unroll") \
  for(int ks=0; ks<2; ks++){ \
    _Pragma("unroll") \
    for(int mf=0; mf<4; mf++){ \
      _Pragma("unroll") \
      for(int nf=0; nf<2; nf++){ \
        acc[(MH)*4+mf][(NH)*2+nf] = __builtin_amdgcn_mfma_f32_16x16x32_bf16( \
            af[mf][ks], bf[(NH)*2+nf][ks], acc[(MH)*4+mf][(NH)*2+nf], 0,0,0); \
      } } } \
  __builtin_amdgcn_s_setprio(0); \
}while(0)

  f32x4 acc[8][4] = {};
  s16x8 af[4][2], bf[4][2];
  const unsigned short* baseA0 = &L[wm<<1][0];
  const unsigned short* baseB0 = &L[4 + ((wn>>1)<<1)][0];

  // prologue: tile0 (4 halves) + tile1's B-h0,B-h1,A-h0 => 14 loads, keep 6 in flight
  STAGE_A(0, 0, 0); STAGE_A(1, 0, 0); STAGE_B(0, 0, 0); STAGE_B(1, 0, 0);
  STAGE_B(0, 1, 1); STAGE_B(1, 1, 1); STAGE_A(0, 1, 1);
  asm volatile("s_waitcnt vmcnt(6)" ::: "memory");
  __builtin_amdgcn_s_barrier();

  for(int g=0; g<12; ++g){
    const int s = g&1;
    const unsigned short* baseA = baseA0 + (s<<13);
    const unsigned short* baseB = baseB0 + (s<<13);
    // ---- P1: read A-mh0 + B-all; stage A-h1(g+1) -> slot s^1
    READ_A(0);
    READ_B();
    if(g<11){ STAGE_A(1, g+1, s^1); }
    __builtin_amdgcn_s_barrier();
    asm volatile("s_waitcnt lgkmcnt(0)" ::: "memory");
    __builtin_amdgcn_sched_barrier(0);
    MMA_Q(0,0);
    __builtin_amdgcn_s_barrier();
    // ---- P2: stage B-h0(g+2) -> slot s
    if(g<10){ STAGE_B(0, g+2, s); }
    __builtin_amdgcn_s_barrier();
    MMA_Q(0,1);
    __builtin_amdgcn_s_barrier();
    // ---- P3: read A-mh1; stage B-h1(g+2) -> slot s
    READ_A(1);
    if(g<10){ STAGE_B(1, g+2, s); }
    __builtin_amdgcn_s_barrier();
    asm volatile("s_waitcnt lgkmcnt(0)" ::: "memory");
    __builtin_amdgcn_sched_barrier(0);
    MMA_Q(1,1);
    __builtin_amdgcn_s_barrier();
    // ---- P4: stage A-h0(g+2) -> slot s; counted vmcnt
    if(g<10){
      STAGE_A(0, g+2, s);
      asm volatile("s_waitcnt vmcnt(6)" ::: "memory");
    } else if(g==10){
      asm volatile("s_waitcnt vmcnt(0)" ::: "memory");
    }
    __builtin_amdgcn_s_barrier();
    MMA_Q(1,0);
    __builtin_amdgcn_s_barrier();
  }

  // ---- epilogue: rows m0+wm*128+mi*16+lq*4+r, cols n0+wn*64+ni*16+lr
  if(n0 >= 1536){
    // transposed V write: vtbuf[b*768 + (nc-1536)][token], 4 consecutive tokens/lane
    #pragma unroll
    for(int mi=0; mi<8; mi++){
      int tok0 = m0 + wm*128 + mi*16 + lq*4;
      int b0 = tok0/577, t0 = tok0 - b0*577;
      bool fast = (tok0 + 3 < M_) && (t0 + 3 < 577);
      #pragma unroll
      for(int ni=0; ni<4; ni++){
        int vrow = (n0 - 1536) + wn*64 + ni*16 + lr;
        ushort4 pk; unsigned short* pks = (unsigned short*)&pk;
        #pragma unroll
        for(int r=0;r<4;r++) pks[r] = f2bf(acc[mi][ni][r]);
        if(fast){
          *(ushort4*)&vtbuf[(size_t)(b0*768 + vrow)*VTLD + t0] = pk;
        } else {
          #pragma unroll
          for(int r=0;r<4;r++){
            int tg = tok0 + r;
            if(tg < M_){
              int bb = tg/577, tt = tg - bb*577;
              vtbuf[(size_t)(bb*768 + vrow)*VTLD + tt] = pks[r];
            }
          }
        }
      }
    }
  } else {
    #pragma unroll
    for(int mi=0; mi<8; mi++){
      #pragma unroll
      for(int r=0;r<4;r++){
        int row = m0 + wm*128 + mi*16 + lq*4 + r;
        if(row < M_){
          #pragma unroll
          for(int ni=0; ni<4; ni++){
            int col = n0 + wn*64 + ni*16 + lr;
            qkvb[(size_t)row*2304 + col] = f2bf(acc[mi][ni][r]);
          }
        }
      }
    }
  }
#undef STAGE_A
#undef STAGE_B
#undef READ_A
#undef READ_B
#undef MMA_Q
}

// ---------------- bf16 MFMA GEMM, 64x128 tile (for parallelism-starved GEMM2) ----------------
// wave-tile 32x64 (acc 2x4 = 32 AGPR). f32 out + bias.
__global__ __launch_bounds__(256) void k_gemm_bt64(const unsigned short* __restrict__ A,
                          const unsigned short* __restrict__ Bt,
                          float* __restrict__ Cout,
                          const float* __restrict__ bias, int Mdim){
  __shared__ __align__(16) unsigned short As[64*32];    // 4 KB
  __shared__ __align__(16) unsigned short Bs[128*32];   // 8 KB
  const int t = threadIdx.x;
  const int w = t>>6, l = t&63, lq = l>>4, lr = l&15;
  const int wm = w>>1, wn = w&1;                        // wave-tile rows wm*32, cols wn*64
  int mt, nt; tile_map<6, 18, 145>(blockIdx.x, mt, nt);
  const int m0 = mt*64, n0 = nt*128;
  int rA0 = m0 + (t>>2);       if(rA0 >= Mdim) rA0 = Mdim-1;
  const unsigned short* gA0 = A  + (size_t)rA0*768 + (t&3)*8;
  const unsigned short* gB0 = Bt + (size_t)(n0 + (t>>2))*768 + (t&3)*8;
  const unsigned short* gB1 = Bt + (size_t)(n0 + ((t+256)>>2))*768 + (t&3)*8;
  unsigned short* lA0 = As + (size_t)w*512;
  unsigned short* lB0 = Bs + (size_t)w*512;
  unsigned short* lB1 = Bs + 2048 + (size_t)w*512;
  f32x4 acc[2][4] = {};
  for(int kt=0; kt<24; ++kt){
    const int ko = kt*32;
    __syncthreads();
    gld_lds16(gA0 + ko, lA0);
    gld_lds16(gB0 + ko, lB0); gld_lds16(gB1 + ko, lB1);
    __syncthreads();
    s16x8 af[2], bfr[4];
    #pragma unroll
    for(int it=0;it<2;it++) af[it]  = *(const s16x8*)&As[(wm*32+it*16+lr)*32 + lq*8];
    #pragma unroll
    for(int jt=0;jt<4;jt++) bfr[jt] = *(const s16x8*)&Bs[(wn*64+jt*16+lr)*32 + lq*8];
    #pragma unroll
    for(int it=0;it<2;it++)
      #pragma unroll
      for(int jt=0;jt<4;jt++)
        acc[it][jt] = __builtin_amdgcn_mfma_f32_16x16x32_bf16(af[it], bfr[jt], acc[it][jt], 0,0,0);
  }
  #pragma unroll
  for(int it=0;it<2;it++){
    #pragma unroll
    for(int r=0;r<4;r++){
      int row = m0 + wm*32 + it*16 + lq*4 + r;
      if(row < Mdim){
        #pragma unroll
        for(int jt=0;jt<4;jt++){
          int col = n0 + wn*64 + jt*16 + lr;
          Cout[(size_t)row*768 + col] = acc[it][jt][r] + bias[col];
        }
      }
    }
  }
}

// ---------------- fused flash attention, max-free softmax, S^T, peeled edge tile ----------------
__global__ __launch_bounds__(256,4) void k_attn(const unsigned short* __restrict__ qkv,
                                                const unsigned short* __restrict__ vtbuf,
                                                unsigned short* __restrict__ aout){
  __shared__ __align__(16) unsigned short Ks[64*64];
  __shared__ __align__(16) unsigned short Vt[64*64];
  __shared__ __align__(16) unsigned short Ptt[128*PTLD];
  __shared__ float Ls[4][2][16][4];
  const int blk = blockIdx.x;
  const int bh = blk % 192, qt = blk / 192;
  const int b = bh / 12, h = bh % 12;
  const int t = threadIdx.x, w = t>>6, l = t&63, lq = l>>4, lr = l&15;
  const size_t base = (size_t)(b*577)*2304 + h*64;
  const int q0 = qt*128;
  s16x8 bq[2][2];
  #pragma unroll
  for(int it=0;it<2;it++){
    int qrow = q0 + w*32 + it*16 + lr; if(qrow > 576) qrow = 576;
    #pragma unroll
    for(int ks=0;ks<2;ks++)
      bq[it][ks] = *(const s16x8*)&qkv[base + (size_t)qrow*2304 + ks*32 + lq*8];
  }
  const int srow = w*8 + (l>>3);
  const int cswz8 = (((l&7) ^ (l>>3)) << 3);
  unsigned short* ldsK = Ks + (size_t)w*512;
  unsigned short* ldsV = Vt + (size_t)w*512;
  const unsigned short* gVbase = vtbuf + (size_t)(bh*64)*VTLD + cswz8;

  f32x4 acc_o[2][4] = {};
  float lsum[2] = {0.f, 0.f};
  const float CEXP = 0.18033688011112043f;              // 0.125 * log2(e)

  auto tile_body = [&](int j0, bool edge){
    __syncthreads();
    #pragma unroll
    for(int i=0;i<2;i++){
      int krow = j0 + i*32 + srow; if(krow > 576) krow = 576;
      gld_lds16(qkv + base + 768 + (size_t)krow*2304 + cswz8, ldsK + i*2048);
      gld_lds16(gVbase + (size_t)(i*32 + srow)*VTLD + j0,     ldsV + i*2048);
    }
    __syncthreads();
    f32x4 accs[2][4] = {};
    #pragma unroll
    for(int ks=0;ks<2;ks++){
      s16x8 ak[4];
      #pragma unroll
      for(int jt=0;jt<4;jt++){
        int j = jt*16 + lr;
        ak[jt] = *(const s16x8*)&Ks[j*64 + (((4*ks+lq) ^ (j&7))<<3)];
      }
      #pragma unroll
      for(int it=0;it<2;it++)
        #pragma unroll
        for(int jt=0;jt<4;jt++)
          accs[it][jt] = __builtin_amdgcn_mfma_f32_16x16x32_bf16(ak[jt], bq[it][ks], accs[it][jt], 0,0,0);
    }
    #pragma unroll
    for(int it=0;it<2;it++){
      int qlocal = w*32 + it*16 + lr;
      #pragma unroll
      for(int jt=0;jt<4;jt++){
        ushort4 pk;
        unsigned short* pks = (unsigned short*)&pk;
        #pragma unroll
        for(int r=0;r<4;r++){
          float p = exp2f(accs[it][jt][r] * CEXP);
          if(edge){ if(j0 + jt*16 + lq*4 + r > 576) p = 0.f; }
          lsum[it] += p;
          pks[r] = f2bf(p);
        }
        *(ushort4*)&Ptt[qlocal*PTLD + jt*16 + lq*4] = pk;
      }
    }
    #pragma unroll
    for(int ks=0;ks<2;ks++){
      s16x8 ap[2], bv[4];
      #pragma unroll
      for(int it=0;it<2;it++)
        ap[it] = *(const s16x8*)&Ptt[(w*32+it*16+lr)*PTLD + ks*32 + lq*8];
      #pragma unroll
      for(int dt=0;dt<4;dt++){
        int d = dt*16 + lr;
        bv[dt] = *(const s16x8*)&Vt[d*64 + (((4*ks+lq) ^ (d&7))<<3)];
      }
      #pragma unroll
      for(int it=0;it<2;it++)
        #pragma unroll
        for(int dt=0;dt<4;dt++)
          acc_o[it][dt] = __builtin_amdgcn_mfma_f32_16x16x32_bf16(ap[it], bv[dt], acc_o[it][dt], 0,0,0);
    }
  };
  for(int j0=0; j0<576; j0+=64) tile_body(j0, false);   // j <= 575: no masking needed
  tile_body(576, true);                                 // edge tile: only j=576 valid

  #pragma unroll
  for(int it=0;it<2;it++) Ls[w][it][lr][lq] = lsum[it];
  #pragma unroll
  for(int it=0;it<2;it++){
    #pragma unroll
    for(int r=0;r<4;r++){
      int n = q0 + w*32 + it*16 + lq*4 + r;
      if(n <= 576){
        int q16 = lq*4 + r;
        float lt = Ls[w][it][q16][0] + Ls[w][it][q16][1] + Ls[w][it][q16][2] + Ls[w][it][q16][3];
        float inv = 1.f / lt;
        #pragma unroll
        for(int dt=0;dt<4;dt++)
          aout[(size_t)(b*577+n)*768 + h*64 + dt*16 + lr] = f2bf(acc_o[it][dt][r]*inv);
      }
    }
  }
}

// ---------------- fp32 top-k path (exact ranking) ----------------
__global__ void k_qcls(const float* __restrict__ x, const float* __restrict__ Wqkv,
                       float* __restrict__ qcls){
  __shared__ float xs[768];
  __shared__ float part[4][64];
  const int b = blockIdx.y, j0 = blockIdx.x*64;
  const int t = threadIdx.x;
  const float* xr = x + (size_t)b*577*768;
  xs[t] = xr[t]; xs[t+256] = xr[t+256]; xs[t+512] = xr[t+512];
  __syncthreads();
  const int jl = t & 63, cs = t >> 6;
  float acc = 0.f;
  const float* wp = Wqkv + (size_t)(cs*192)*2304 + j0 + jl;
  #pragma unroll 4
  for(int c=0;c<192;c++){ acc += xs[cs*192+c] * wp[0]; wp += 2304; }
  part[cs][jl] = acc;
  __syncthreads();
  if(t < 64) qcls[b*768 + j0 + t] = part[0][t]+part[1][t]+part[2][t]+part[3][t];
}
__global__ void k_u(const float* __restrict__ Wqkv, const float* __restrict__ qcls,
                    float* __restrict__ u){
  int h = blockIdx.x, b = blockIdx.y, c = threadIdx.x;  // 768 threads
  const float* qc = qcls + b*768 + h*64;
  const float* wr = Wqkv + (size_t)c*2304 + 768 + h*64;
  float acc = 0.f;
  #pragma unroll
  for(int d=0;d<64;d++) acc += wr[d]*qc[d];
  u[(size_t)(b*12+h)*768 + c] = acc;
}
__global__ void k_attw(const float* __restrict__ x, const float* __restrict__ u,
                       float* __restrict__ attw){
  int blk = blockIdx.x;               // 16*577 blocks of 1 wave
  int b = blk/577, m = blk%577;
  int lane = threadIdx.x;
  const float* xr = x + (size_t)(b*577+m)*768;
  const float* ub = u + (size_t)b*12*768;
  float part[12];
  #pragma unroll
  for(int h=0;h<12;h++) part[h]=0.f;
  #pragma unroll
  for(int i=0;i<12;i++){
    float xv = xr[i*64 + lane];
    #pragma unroll
    for(int h=0;h<12;h++) part[h] += xv * ub[h*768 + i*64 + lane];
  }
  float s = 0.f;
  #pragma unroll
  for(int h=0;h<12;h++){
    float v = part[h];
    #pragma unroll
    for(int off=32; off; off>>=1) v += __shfl_xor(v, off);
    s += fabsf(v);
  }
  if(lane==0) attw[b*577 + m] = 0.125f * s;
}
__global__ void k_topk(const float* __restrict__ attw, int* __restrict__ idxbuf){
  __shared__ float sw[576];
  __shared__ int wtot[9];
  int b = blockIdx.x, t = threadIdx.x;     // 576 threads
  float wv = attw[b*577 + 1 + t];
  sw[t] = wv;
  __syncthreads();
  int rank = 0;
  for(int j=0;j<576;j++){
    float wj = sw[j];
    rank += (wj > wv) || (wj == wv && j < t);
  }
  bool kept = rank < NKEEP;
  unsigned long long mask = __ballot(kept);
  int wid = t>>6, lane = t&63;
  int pos = __popcll(mask & ((1ull<<lane)-1ull));
  if(lane==0) wtot[wid] = __popcll(mask);
  __syncthreads();
  int off0 = 0;
  for(int q=0;q<wid;q++) off0 += wtot[q];
  if(kept) idxbuf[b*KROWS + 1 + off0 + pos] = t+1;
  if(t==0) idxbuf[b*KROWS] = 0;
}
__global__ void k_fill_keep(const int* __restrict__ idxbuf, float* __restrict__ out2){
  int i4 = blockIdx.x*256 + threadIdx.x;
  float v = (float)idxbuf[i4/192];
  ((float4*)out2)[i4] = make_float4(v,v,v,v);
}

extern "C" void kernel_launch(void* const* d_in, const int* in_sizes, int n_in,
                              void* d_out, int out_size, void* d_ws, size_t ws_size,
                              hipStream_t stream){
  const float* x     = (const float*)d_in[0];
  const float* Wqkv  = (const float*)d_in[1];
  const float* Wproj = (const float*)d_in[2];
  const float* bias  = (const float*)d_in[3];
  float* out  = (float*)d_out;
  float* out2 = out + (size_t)M_*768;      // keep_index chunk (float32)

  char* ws = (char*)d_ws;
  size_t off = 0;
  auto alloc = [&](size_t bytes)->void*{ void* p = ws + off; off += (bytes + 255) & ~(size_t)255; return p; };
  unsigned short* xb     = (unsigned short*)alloc((size_t)M_*768*2);
  unsigned short* wqkvT  = (unsigned short*)alloc((size_t)QKVN*768*2);
  unsigned short* wprojT = (unsigned short*)alloc((size_t)768*768*2);
  unsigned short* qkvb   = (unsigned short*)alloc((size_t)M_*QKVN*2);
  unsigned short* aoutb  = (unsigned short*)alloc((size_t)M_*768*2);
  unsigned short* vtbuf  = (unsigned short*)alloc((size_t)192*64*VTLD*2);
  float* qcls   = (float*)alloc((size_t)16*768*4);
  float* u      = (float*)alloc((size_t)16*12*768*4);
  float* attw   = (float*)alloc((size_t)16*577*4);
  int*   idxbuf = (int*)alloc((size_t)16*KROWS*4);

  // bf16 casts / transposes
  k_cvt_x<<<6924, 256, 0, stream>>>(x, xb);
  k_transpose_cvt<<<dim3(36,12), 256, 0, stream>>>(Wqkv,  wqkvT, 768, 2304);
  k_transpose_cvt<<<dim3(12,12), 256, 0, stream>>>(Wproj, wprojT, 768, 768);
  // QKV GEMM (bf16 out; V-tiles written transposed into vtbuf). 256x256 8-phase tiles.
  k_gemm_qkv<<<333, 512, 0, stream>>>(xb, wqkvT, qkvb, vtbuf);
  // fp32 top-k weight path
  k_qcls<<<dim3(12,16), 256, 0, stream>>>(x, Wqkv, qcls);
  k_u<<<dim3(12,16), 768, 0, stream>>>(Wqkv, qcls, u);
  k_attw<<<16*577, 64, 0, stream>>>(x, u, attw);
  k_topk<<<16, 576, 0, stream>>>(attw, idxbuf);
  k_fill_keep<<<(16*KROWS*768/4 + 255)/256, 256, 0, stream>>>(idxbuf, out2);
  // attention + out-proj
  k_attn<<<960, 256, 0, stream>>>(qkvb, vtbuf, aoutb);
  k_gemm_bt64<<<145*6, 256, 0, stream>>>(aoutb, wprojT, out, bias, M_);
}

// Round 2
// 294.740 us; speedup vs baseline: 1.0019x; 1.0019x over previous
//
#include <hip/hip_runtime.h>
#include <hip/hip_bf16.h>
#include <stdint.h>

// Problem constants
#define B_    16
#define N_    577
#define C_    768
#define H_    12
#define M_    (B_*N_)     // 9232 rows
#define QKVN  (3*C_)      // 2304
#define NKEEP 403         // int(576*0.7)
#define KROWS (NKEEP+1)   // 404
#define VTLD  640         // vtbuf padded row length
#define PTLD  72          // Ptt row stride (ushorts)

typedef short s16x8 __attribute__((ext_vector_type(8)));
typedef float f32x4 __attribute__((ext_vector_type(4)));

__device__ __forceinline__ unsigned short f2bf(float x){
  unsigned int u = __float_as_uint(x);
  u += 0x7FFF + ((u >> 16) & 1);          // round-to-nearest-even
  return (unsigned short)(u >> 16);
}

// async global->LDS, 16B per lane; lds dest = wave-uniform base + lane*16
__device__ __forceinline__ void gld_lds16(const void* g, void* l){
  __builtin_amdgcn_global_load_lds(
      (const __attribute__((address_space(1))) unsigned int*)g,
      (__attribute__((address_space(3))) unsigned int*)l, 16, 0, 0);
}

// Generic XCD-panel tile mapping (used by k_gemm_bt64)
template<int NT, int M9, int MTILES>
__device__ __forceinline__ void tile_map(int L, int& mt, int& nt){
  constexpr int NB = MTILES*NT;
  int x = L & 7, j = L >> 3;
  if(j < M9*NT){
    nt = j/M9; mt = x*M9 + (j - nt*M9);    // n-outer: M9 consecutive blocks share B-tile
  } else {
    int offt = 0;
    #pragma unroll
    for(int y=0;y<8;y++) if(y<x) offt += ((NB-1-y)>>3) + 1 - M9*NT;  // tail_y
    int ft = offt + (j - M9*NT);
    mt = 8*M9 + ft/NT;
    nt = ft - (ft/NT)*NT;
  }
}

// ---------------- cast x -> bf16 (vectorized) ----------------
__global__ void k_cvt_x(const float* __restrict__ x, unsigned short* __restrict__ xb){
  int i = blockIdx.x*256 + threadIdx.x;
  float4 v = ((const float4*)x)[i];
  ushort4 o; o.x=f2bf(v.x); o.y=f2bf(v.y); o.z=f2bf(v.z); o.w=f2bf(v.w);
  ((ushort4*)xb)[i] = o;
}

// ------------- transpose+cast weights: out[c][r] = bf16(in[r][c]) -------------
__global__ void k_transpose_cvt(const float* __restrict__ in, unsigned short* __restrict__ out,
                                int R, int CC){
  __shared__ float tile[64][65];
  int r0 = blockIdx.y*64, c0 = blockIdx.x*64;
  int tx = threadIdx.x & 63, ty = threadIdx.x >> 6;
  #pragma unroll
  for(int i=0;i<16;i++){
    int r = ty + i*4;
    tile[r][tx] = in[(size_t)(r0+r)*CC + c0 + tx];
  }
  __syncthreads();
  #pragma unroll
  for(int i=0;i<16;i++){
    int c = ty + i*4;
    out[(size_t)(c0+c)*R + r0 + tx] = f2bf(tile[tx][c]);
  }
}

// =================================================================================
// QKV GEMM: 256x256 tile, BK=64, 8 waves (2Mx4N), 8-phase counted-vmcnt schedule.
// LDS = 8 units of 16KB:
//   unit (h*2|s)   : A half h (128 rows x 64 k), k-tile parity s
//   unit 4+(h*2|s) : B half h (128 cols x 64 k), k-tile parity s
// T2 swizzle (FIXED r2): element (row,kc) stored at ushort col kc ^ SWZ(row),
//   SWZ(row) = ((row&1)<<5) | (((row>>1)&3)<<3)  [byte bits 6:4 ^= row bits 2:0]
// -> fragment ds_read_b128: bank-group id = (row&1)*4 + (lq ^ ((row>>1)&3)):
//    8 groups x 8 lanes = uniform 8 accesses/bank = conflict-free floor.
// LDS stays linear for global_load_lds; global SOURCE col is pre-XORed with the
// same mask (involution), so staged bytes land where the reads expect them.
// Rows r and r+64 share SWZ (bit6 of row doesn't enter), so both halves of a
// 128-row unit use one lane mapping.
// Stage ledger (group g computes k-tile g, slot s=g&1):
//   P1: read A-mh0(8) + B-all(8); stage A-h1(g+1)->s^1
//   P2: stage B-h0(g+2)->s
//   P3: read A-mh1(8);           stage B-h1(g+2)->s
//   P4: stage A-h0(g+2)->s; s_waitcnt vmcnt(6)   (3 half-tiles = 6 loads in flight)
// Tail: g=10 stages only P1 and uses vmcnt(0); g=11 stages nothing.
// V-tiles (n0>=1536) written transposed into vtbuf (FUSEV), rest bf16 into qkvb.
// =================================================================================
__global__ __launch_bounds__(512,2) void k_gemm_qkv(const unsigned short* __restrict__ A,
                          const unsigned short* __restrict__ Bt,
                          unsigned short* __restrict__ qkvb,
                          unsigned short* __restrict__ vtbuf){
  __shared__ __align__(16) unsigned short L[8][8192];   // 128 KiB
  const int t = threadIdx.x;
  const int w = t>>6, l = t&63, lq = l>>4, lr = l&15;
  const int wm = w>>2, wn = w&3;

  // block mapping: bijective XCD swizzle (333 = 8*41+5), m-outer (A-panel sharing)
  int orig = blockIdx.x;
  int xid = orig & 7, j = orig >> 3;
  int wgid = (xid < 5 ? xid*42 : 210 + (xid-5)*41) + j;
  int mt = wgid/9, nt = wgid - mt*9;
  const int m0 = mt*256, n0 = nt*256;

  // staging: lane covers row rr = w*8+(l>>3), 16B chunk (l&7); source pre-swizzled
  // with SWZ(rr) = ((rr&1)<<5)|(((rr>>1)&3)<<3) = (((l>>3)&1)<<5)|(((l>>4)&3)<<3)
  const int rr = w*8 + (l>>3);
  const int csw = ((l&7)<<3) ^ ((((l>>3)&1)<<5) | (((l>>4)&3)<<3));
  int ra0 = m0 + rr;        if(ra0 >= M_) ra0 = M_-1;
  int ra1 = m0 + 64 + rr;   if(ra1 >= M_) ra1 = M_-1;
  int ra2 = m0 + 128 + rr;  if(ra2 >= M_) ra2 = M_-1;
  int ra3 = m0 + 192 + rr;  if(ra3 >= M_) ra3 = M_-1;
  const unsigned short* pA00 = A + (size_t)ra0*768 + csw;  // h0 c0
  const unsigned short* pA01 = A + (size_t)ra1*768 + csw;  // h0 c1
  const unsigned short* pA10 = A + (size_t)ra2*768 + csw;  // h1 c0
  const unsigned short* pA11 = A + (size_t)ra3*768 + csw;  // h1 c1
  const unsigned short* pB00 = Bt + (size_t)(n0 + rr)*768 + csw;
  const unsigned short* pB01 = Bt + (size_t)(n0 + 64 + rr)*768 + csw;
  const unsigned short* pB10 = Bt + (size_t)(n0 + 128 + rr)*768 + csw;
  const unsigned short* pB11 = Bt + (size_t)(n0 + 192 + rr)*768 + csw;

  // fragment-read swizzle: R_ = *+16*mf+lr => R_&1 = lr&1, (R_>>1)&3 = (lr>>1)&3
  const int fswz = ((lr&1)<<5) | (((lr>>1)&3)<<3);

#define STAGE_A(H, KT, SLT) do{ \
  unsigned short* d_ = &L[((H)<<1)|(SLT)][(w*8)<<6]; \
  gld_lds16(pA##H##0 + (size_t)(KT)*64, d_); \
  gld_lds16(pA##H##1 + (size_t)(KT)*64, d_ + 4096); \
}while(0)
#define STAGE_B(H, KT, SLT) do{ \
  unsigned short* d_ = &L[4 + (((H)<<1)|(SLT))][(w*8)<<6]; \
  gld_lds16(pB##H##0 + (size_t)(KT)*64, d_); \
  gld_lds16(pB##H##1 + (size_t)(KT)*64, d_ + 4096); \
}while(0)
#define READ_A(MH) do{ \
  _Pragma("unroll") \
  for(int mf=0; mf<4; mf++){ \
    const int R_ = (MH)*64 + mf*16 + lr; \
    af[mf][0] = *(const s16x8*)&baseA[R_*64 + ((lq*8) ^ fswz)]; \
    af[mf][1] = *(const s16x8*)&baseA[R_*64 + ((32 + lq*8) ^ fswz)]; \
  } \
}while(0)
#define READ_B() do{ \
  _Pragma("unroll") \
  for(int nf=0; nf<4; nf++){ \
    const int R_ = (wn&1)*64 + nf*16 + lr; \
    bf[nf][0] = *(const s16x8*)&baseB[R_*64 + ((lq*8) ^ fswz)]; \
    bf[nf][1] = *(const s16x8*)&baseB[R_*64 + ((32 + lq*8) ^ fswz)]; \
  } \
}while(0)
#define MMA_Q(MH, NH) do{ \
  __builtin_amdgcn_s_setprio(1); \
  _Pragma("unroll") \
  for(int ks=0; ks<2; ks++){ \
    _Pragma("unroll") \
    for(int mf=0; mf<4; mf++){ \
      _Pragma("unroll") \
      for(int nf=0; nf<2; nf++){ \
        acc[(MH)*4+mf][(NH)*2+nf] = __builtin_amdgcn_mfma_f32_16x16x32_bf16( \
            af[mf][ks], bf[(NH)*2+nf][ks], acc[(MH)*4+mf][(NH)*2+nf], 0,0,0); \
      } } } \
  __builtin_amdgcn_s_setprio(0); \
}while(0)

  f32x4 acc[8][4] = {};
  s16x8 af[4][2], bf[4][2];
  const unsigned short* baseA0 = &L[wm<<1][0];
  const unsigned short* baseB0 = &L[4 + ((wn>>1)<<1)][0];

  // prologue: tile0 (4 halves) + tile1's B-h0,B-h1,A-h0 => 14 loads, keep 6 in flight
  STAGE_A(0, 0, 0); STAGE_A(1, 0, 0); STAGE_B(0, 0, 0); STAGE_B(1, 0, 0);
  STAGE_B(0, 1, 1); STAGE_B(1, 1, 1); STAGE_A(0, 1, 1);
  asm volatile("s_waitcnt vmcnt(6)" ::: "memory");
  __builtin_amdgcn_s_barrier();

  for(int g=0; g<12; ++g){
    const int s = g&1;
    const unsigned short* baseA = baseA0 + (s<<13);
    const unsigned short* baseB = baseB0 + (s<<13);
    // ---- P1: read A-mh0 + B-all; stage A-h1(g+1) -> slot s^1
    READ_A(0);
    READ_B();
    if(g<11){ STAGE_A(1, g+1, s^1); }
    __builtin_amdgcn_s_barrier();
    asm volatile("s_waitcnt lgkmcnt(0)" ::: "memory");
    __builtin_amdgcn_sched_barrier(0);
    MMA_Q(0,0);
    __builtin_amdgcn_s_barrier();
    // ---- P2: stage B-h0(g+2) -> slot s
    if(g<10){ STAGE_B(0, g+2, s); }
    __builtin_amdgcn_s_barrier();
    MMA_Q(0,1);
    __builtin_amdgcn_s_barrier();
    // ---- P3: read A-mh1; stage B-h1(g+2) -> slot s
    READ_A(1);
    if(g<10){ STAGE_B(1, g+2, s); }
    __builtin_amdgcn_s_barrier();
    asm volatile("s_waitcnt lgkmcnt(0)" ::: "memory");
    __builtin_amdgcn_sched_barrier(0);
    MMA_Q(1,1);
    __builtin_amdgcn_s_barrier();
    // ---- P4: stage A-h0(g+2) -> slot s; counted vmcnt
    if(g<10){
      STAGE_A(0, g+2, s);
      asm volatile("s_waitcnt vmcnt(6)" ::: "memory");
    } else if(g==10){
      asm volatile("s_waitcnt vmcnt(0)" ::: "memory");
    }
    __builtin_amdgcn_s_barrier();
    MMA_Q(1,0);
    __builtin_amdgcn_s_barrier();
  }

  // ---- epilogue: rows m0+wm*128+mi*16+lq*4+r, cols n0+wn*64+ni*16+lr
  if(n0 >= 1536){
    // transposed V write: vtbuf[b*768 + (nc-1536)][token], 4 consecutive tokens/lane
    #pragma unroll
    for(int mi=0; mi<8; mi++){
      int tok0 = m0 + wm*128 + mi*16 + lq*4;
      int b0 = tok0/577, t0 = tok0 - b0*577;
      bool fast = (tok0 + 3 < M_) && (t0 + 3 < 577);
      #pragma unroll
      for(int ni=0; ni<4; ni++){
        int vrow = (n0 - 1536) + wn*64 + ni*16 + lr;
        ushort4 pk; unsigned short* pks = (unsigned short*)&pk;
        #pragma unroll
        for(int r=0;r<4;r++) pks[r] = f2bf(acc[mi][ni][r]);
        if(fast){
          *(ushort4*)&vtbuf[(size_t)(b0*768 + vrow)*VTLD + t0] = pk;
        } else {
          #pragma unroll
          for(int r=0;r<4;r++){
            int tg = tok0 + r;
            if(tg < M_){
              int bb = tg/577, tt = tg - bb*577;
              vtbuf[(size_t)(bb*768 + vrow)*VTLD + tt] = pks[r];
            }
          }
        }
      }
    }
  } else {
    #pragma unroll
    for(int mi=0; mi<8; mi++){
      #pragma unroll
      for(int r=0;r<4;r++){
        int row = m0 + wm*128 + mi*16 + lq*4 + r;
        if(row < M_){
          #pragma unroll
          for(int ni=0; ni<4; ni++){
            int col = n0 + wn*64 + ni*16 + lr;
            qkvb[(size_t)row*2304 + col] = f2bf(acc[mi][ni][r]);
          }
        }
      }
    }
  }
#undef STAGE_A
#undef STAGE_B
#undef READ_A
#undef READ_B
#undef MMA_Q
}

// ---------------- bf16 MFMA GEMM, 64x128 tile (for parallelism-starved GEMM2) ----------------
// wave-tile 32x64 (acc 2x4 = 32 AGPR). f32 out + bias.
__global__ __launch_bounds__(256) void k_gemm_bt64(const unsigned short* __restrict__ A,
                          const unsigned short* __restrict__ Bt,
                          float* __restrict__ Cout,
                          const float* __restrict__ bias, int Mdim){
  __shared__ __align__(16) unsigned short As[64*32];    // 4 KB
  __shared__ __align__(16) unsigned short Bs[128*32];   // 8 KB
  const int t = threadIdx.x;
  const int w = t>>6, l = t&63, lq = l>>4, lr = l&15;
  const int wm = w>>1, wn = w&1;                        // wave-tile rows wm*32, cols wn*64
  int mt, nt; tile_map<6, 18, 145>(blockIdx.x, mt, nt);
  const int m0 = mt*64, n0 = nt*128;
  int rA0 = m0 + (t>>2);       if(rA0 >= Mdim) rA0 = Mdim-1;
  const unsigned short* gA0 = A  + (size_t)rA0*768 + (t&3)*8;
  const unsigned short* gB0 = Bt + (size_t)(n0 + (t>>2))*768 + (t&3)*8;
  const unsigned short* gB1 = Bt + (size_t)(n0 + ((t+256)>>2))*768 + (t&3)*8;
  unsigned short* lA0 = As + (size_t)w*512;
  unsigned short* lB0 = Bs + (size_t)w*512;
  unsigned short* lB1 = Bs + 2048 + (size_t)w*512;
  f32x4 acc[2][4] = {};
  for(int kt=0; kt<24; ++kt){
    const int ko = kt*32;
    __syncthreads();
    gld_lds16(gA0 + ko, lA0);
    gld_lds16(gB0 + ko, lB0); gld_lds16(gB1 + ko, lB1);
    __syncthreads();
    s16x8 af[2], bfr[4];
    #pragma unroll
    for(int it=0;it<2;it++) af[it]  = *(const s16x8*)&As[(wm*32+it*16+lr)*32 + lq*8];
    #pragma unroll
    for(int jt=0;jt<4;jt++) bfr[jt] = *(const s16x8*)&Bs[(wn*64+jt*16+lr)*32 + lq*8];
    #pragma unroll
    for(int it=0;it<2;it++)
      #pragma unroll
      for(int jt=0;jt<4;jt++)
        acc[it][jt] = __builtin_amdgcn_mfma_f32_16x16x32_bf16(af[it], bfr[jt], acc[it][jt], 0,0,0);
  }
  #pragma unroll
  for(int it=0;it<2;it++){
    #pragma unroll
    for(int r=0;r<4;r++){
      int row = m0 + wm*32 + it*16 + lq*4 + r;
      if(row < Mdim){
        #pragma unroll
        for(int jt=0;jt<4;jt++){
          int col = n0 + wn*64 + jt*16 + lr;
          Cout[(size_t)row*768 + col] = acc[it][jt][r] + bias[col];
        }
      }
    }
  }
}

// ---------------- fused flash attention, max-free softmax, S^T, peeled edge tile ----------------
__global__ __launch_bounds__(256,4) void k_attn(const unsigned short* __restrict__ qkv,
                                                const unsigned short* __restrict__ vtbuf,
                                                unsigned short* __restrict__ aout){
  __shared__ __align__(16) unsigned short Ks[64*64];
  __shared__ __align__(16) unsigned short Vt[64*64];
  __shared__ __align__(16) unsigned short Ptt[128*PTLD];
  __shared__ float Ls[4][2][16][4];
  const int blk = blockIdx.x;
  const int bh = blk % 192, qt = blk / 192;
  const int b = bh / 12, h = bh % 12;
  const int t = threadIdx.x, w = t>>6, l = t&63, lq = l>>4, lr = l&15;
  const size_t base = (size_t)(b*577)*2304 + h*64;
  const int q0 = qt*128;
  s16x8 bq[2][2];
  #pragma unroll
  for(int it=0;it<2;it++){
    int qrow = q0 + w*32 + it*16 + lr; if(qrow > 576) qrow = 576;
    #pragma unroll
    for(int ks=0;ks<2;ks++)
      bq[it][ks] = *(const s16x8*)&qkv[base + (size_t)qrow*2304 + ks*32 + lq*8];
  }
  const int srow = w*8 + (l>>3);
  const int cswz8 = (((l&7) ^ (l>>3)) << 3);
  unsigned short* ldsK = Ks + (size_t)w*512;
  unsigned short* ldsV = Vt + (size_t)w*512;
  const unsigned short* gVbase = vtbuf + (size_t)(bh*64)*VTLD + cswz8;

  f32x4 acc_o[2][4] = {};
  float lsum[2] = {0.f, 0.f};
  const float CEXP = 0.18033688011112043f;              // 0.125 * log2(e)

  auto tile_body = [&](int j0, bool edge){
    __syncthreads();
    #pragma unroll
    for(int i=0;i<2;i++){
      int krow = j0 + i*32 + srow; if(krow > 576) krow = 576;
      gld_lds16(qkv + base + 768 + (size_t)krow*2304 + cswz8, ldsK + i*2048);
      gld_lds16(gVbase + (size_t)(i*32 + srow)*VTLD + j0,     ldsV + i*2048);
    }
    __syncthreads();
    f32x4 accs[2][4] = {};
    #pragma unroll
    for(int ks=0;ks<2;ks++){
      s16x8 ak[4];
      #pragma unroll
      for(int jt=0;jt<4;jt++){
        int j = jt*16 + lr;
        ak[jt] = *(const s16x8*)&Ks[j*64 + (((4*ks+lq) ^ (j&7))<<3)];
      }
      #pragma unroll
      for(int it=0;it<2;it++)
        #pragma unroll
        for(int jt=0;jt<4;jt++)
          accs[it][jt] = __builtin_amdgcn_mfma_f32_16x16x32_bf16(ak[jt], bq[it][ks], accs[it][jt], 0,0,0);
    }
    #pragma unroll
    for(int it=0;it<2;it++){
      int qlocal = w*32 + it*16 + lr;
      #pragma unroll
      for(int jt=0;jt<4;jt++){
        ushort4 pk;
        unsigned short* pks = (unsigned short*)&pk;
        #pragma unroll
        for(int r=0;r<4;r++){
          float p = exp2f(accs[it][jt][r] * CEXP);
          if(edge){ if(j0 + jt*16 + lq*4 + r > 576) p = 0.f; }
          lsum[it] += p;
          pks[r] = f2bf(p);
        }
        *(ushort4*)&Ptt[qlocal*PTLD + jt*16 + lq*4] = pk;
      }
    }
    #pragma unroll
    for(int ks=0;ks<2;ks++){
      s16x8 ap[2], bv[4];
      #pragma unroll
      for(int it=0;it<2;it++)
        ap[it] = *(const s16x8*)&Ptt[(w*32+it*16+lr)*PTLD + ks*32 + lq*8];
      #pragma unroll
      for(int dt=0;dt<4;dt++){
        int d = dt*16 + lr;
        bv[dt] = *(const s16x8*)&Vt[d*64 + (((4*ks+lq) ^ (d&7))<<3)];
      }
      #pragma unroll
      for(int it=0;it<2;it++)
        #pragma unroll
        for(int dt=0;dt<4;dt++)
          acc_o[it][dt] = __builtin_amdgcn_mfma_f32_16x16x32_bf16(ap[it], bv[dt], acc_o[it][dt], 0,0,0);
    }
  };
  for(int j0=0; j0<576; j0+=64) tile_body(j0, false);   // j <= 575: no masking needed
  tile_body(576, true);                                 // edge tile: only j=576 valid

  #pragma unroll
  for(int it=0;it<2;it++) Ls[w][it][lr][lq] = lsum[it];
  #pragma unroll
  for(int it=0;it<2;it++){
    #pragma unroll
    for(int r=0;r<4;r++){
      int n = q0 + w*32 + it*16 + lq*4 + r;
      if(n <= 576){
        int q16 = lq*4 + r;
        float lt = Ls[w][it][q16][0] + Ls[w][it][q16][1] + Ls[w][it][q16][2] + Ls[w][it][q16][3];
        float inv = 1.f / lt;
        #pragma unroll
        for(int dt=0;dt<4;dt++)
          aout[(size_t)(b*577+n)*768 + h*64 + dt*16 + lr] = f2bf(acc_o[it][dt][r]*inv);
      }
    }
  }
}

// ---------------- fp32 top-k path (exact ranking) ----------------
__global__ void k_qcls(const float* __restrict__ x, const float* __restrict__ Wqkv,
                       float* __restrict__ qcls){
  __shared__ float xs[768];
  __shared__ float part[4][64];
  const int b = blockIdx.y, j0 = blockIdx.x*64;
  const int t = threadIdx.x;
  const float* xr = x + (size_t)b*577*768;
  xs[t] = xr[t]; xs[t+256] = xr[t+256]; xs[t+512] = xr[t+512];
  __syncthreads();
  const int jl = t & 63, cs = t >> 6;
  float acc = 0.f;
  const float* wp = Wqkv + (size_t)(cs*192)*2304 + j0 + jl;
  #pragma unroll 4
  for(int c=0;c<192;c++){ acc += xs[cs*192+c] * wp[0]; wp += 2304; }
  part[cs][jl] = acc;
  __syncthreads();
  if(t < 64) qcls[b*768 + j0 + t] = part[0][t]+part[1][t]+part[2][t]+part[3][t];
}
__global__ void k_u(const float* __restrict__ Wqkv, const float* __restrict__ qcls,
                    float* __restrict__ u){
  int h = blockIdx.x, b = blockIdx.y, c = threadIdx.x;  // 768 threads
  const float* qc = qcls + b*768 + h*64;
  const float* wr = Wqkv + (size_t)c*2304 + 768 + h*64;
  float acc = 0.f;
  #pragma unroll
  for(int d=0;d<64;d++) acc += wr[d]*qc[d];
  u[(size_t)(b*12+h)*768 + c] = acc;
}
__global__ void k_attw(const float* __restrict__ x, const float* __restrict__ u,
                       float* __restrict__ attw){
  int blk = blockIdx.x;               // 16*577 blocks of 1 wave
  int b = blk/577, m = blk%577;
  int lane = threadIdx.x;
  const float* xr = x + (size_t)(b*577+m)*768;
  const float* ub = u + (size_t)b*12*768;
  float part[12];
  #pragma unroll
  for(int h=0;h<12;h++) part[h]=0.f;
  #pragma unroll
  for(int i=0;i<12;i++){
    float xv = xr[i*64 + lane];
    #pragma unroll
    for(int h=0;h<12;h++) part[h] += xv * ub[h*768 + i*64 + lane];
  }
  float s = 0.f;
  #pragma unroll
  for(int h=0;h<12;h++){
    float v = part[h];
    #pragma unroll
    for(int off=32; off; off>>=1) v += __shfl_xor(v, off);
    s += fabsf(v);
  }
  if(lane==0) attw[b*577 + m] = 0.125f * s;
}
__global__ void k_topk(const float* __restrict__ attw, int* __restrict__ idxbuf){
  __shared__ float sw[576];
  __shared__ int wtot[9];
  int b = blockIdx.x, t = threadIdx.x;     // 576 threads
  float wv = attw[b*577 + 1 + t];
  sw[t] = wv;
  __syncthreads();
  int rank = 0;
  for(int j=0;j<576;j++){
    float wj = sw[j];
    rank += (wj > wv) || (wj == wv && j < t);
  }
  bool kept = rank < NKEEP;
  unsigned long long mask = __ballot(kept);
  int wid = t>>6, lane = t&63;
  int pos = __popcll(mask & ((1ull<<lane)-1ull));
  if(lane==0) wtot[wid] = __popcll(mask);
  __syncthreads();
  int off0 = 0;
  for(int q=0;q<wid;q++) off0 += wtot[q];
  if(kept) idxbuf[b*KROWS + 1 + off0 + pos] = t+1;
  if(t==0) idxbuf[b*KROWS] = 0;
}
__global__ void k_fill_keep(const int* __restrict__ idxbuf, float* __restrict__ out2){
  int i4 = blockIdx.x*256 + threadIdx.x;
  float v = (float)idxbuf[i4/192];
  ((float4*)out2)[i4] = make_float4(v,v,v,v);
}

extern "C" void kernel_launch(void* const* d_in, const int* in_sizes, int n_in,
                              void* d_out, int out_size, void* d_ws, size_t ws_size,
                              hipStream_t stream){
  const float* x     = (const float*)d_in[0];
  const float* Wqkv  = (const float*)d_in[1];
  const float* Wproj = (const float*)d_in[2];
  const float* bias  = (const float*)d_in[3];
  float* out  = (float*)d_out;
  float* out2 = out + (size_t)M_*768;      // keep_index chunk (float32)

  char* ws = (char*)d_ws;
  size_t off = 0;
  auto alloc = [&](size_t bytes)->void*{ void* p = ws + off; off += (bytes + 255) & ~(size_t)255; return p; };
  unsigned short* xb     = (unsigned short*)alloc((size_t)M_*768*2);
  unsigned short* wqkvT  = (unsigned short*)alloc((size_t)QKVN*768*2);
  unsigned short* wprojT = (unsigned short*)alloc((size_t)768*768*2);
  unsigned short* qkvb   = (unsigned short*)alloc((size_t)M_*QKVN*2);
  unsigned short* aoutb  = (unsigned short*)alloc((size_t)M_*768*2);
  unsigned short* vtbuf  = (unsigned short*)alloc((size_t)192*64*VTLD*2);
  float* qcls   = (float*)alloc((size_t)16*768*4);
  float* u      = (float*)alloc((size_t)16*12*768*4);
  float* attw   = (float*)alloc((size_t)16*577*4);
  int*   idxbuf = (int*)alloc((size_t)16*KROWS*4);

  // bf16 casts / transposes
  k_cvt_x<<<6924, 256, 0, stream>>>(x, xb);
  k_transpose_cvt<<<dim3(36,12), 256, 0, stream>>>(Wqkv,  wqkvT, 768, 2304);
  k_transpose_cvt<<<dim3(12,12), 256, 0, stream>>>(Wproj, wprojT, 768, 768);
  // QKV GEMM (bf16 out; V-tiles written transposed into vtbuf). 256x256 8-phase tiles.
  k_gemm_qkv<<<333, 512, 0, stream>>>(xb, wqkvT, qkvb, vtbuf);
  // fp32 top-k weight path
  k_qcls<<<dim3(12,16), 256, 0, stream>>>(x, Wqkv, qcls);
  k_u<<<dim3(12,16), 768, 0, stream>>>(Wqkv, qcls, u);
  k_attw<<<16*577, 64, 0, stream>>>(x, u, attw);
  k_topk<<<16, 576, 0, stream>>>(attw, idxbuf);
  k_fill_keep<<<(16*KROWS*768/4 + 255)/256, 256, 0, stream>>>(idxbuf, out2);
  // attention + out-proj
  k_attn<<<960, 256, 0, stream>>>(qkvb, vtbuf, aoutb);
  k_gemm_bt64<<<145*6, 256, 0, stream>>>(aoutb, wprojT, out, bias, M_);
}

// Round 3
// 276.156 us; speedup vs baseline: 1.0693x; 1.0673x over previous
//
#include <hip/hip_runtime.h>
#include <hip/hip_bf16.h>
#include <stdint.h>

// Problem constants
#define B_    16
#define N_    577
#define C_    768
#define H_    12
#define M_    (B_*N_)     // 9232 rows
#define QKVN  (3*C_)      // 2304
#define NKEEP 403         // int(576*0.7)
#define KROWS (NKEEP+1)   // 404
#define VTLD  640         // vtbuf padded row length
#define PTLD  72          // Ptt row stride (ushorts)

typedef short s16x8 __attribute__((ext_vector_type(8)));
typedef float f32x4 __attribute__((ext_vector_type(4)));

__device__ __forceinline__ unsigned short f2bf(float x){
  unsigned int u = __float_as_uint(x);
  u += 0x7FFF + ((u >> 16) & 1);          // round-to-nearest-even
  return (unsigned short)(u >> 16);
}

// async global->LDS, 16B per lane; lds dest = wave-uniform base + lane*16
__device__ __forceinline__ void gld_lds16(const void* g, void* l){
  __builtin_amdgcn_global_load_lds(
      (const __attribute__((address_space(1))) unsigned int*)g,
      (__attribute__((address_space(3))) unsigned int*)l, 16, 0, 0);
}

// Generic XCD-panel tile mapping
template<int NT, int M9, int MTILES>
__device__ __forceinline__ void tile_map(int L, int& mt, int& nt){
  constexpr int NB = MTILES*NT;
  int x = L & 7, j = L >> 3;
  if(j < M9*NT){
    nt = j/M9; mt = x*M9 + (j - nt*M9);    // n-outer: M9 consecutive blocks share B-tile
  } else {
    int offt = 0;
    #pragma unroll
    for(int y=0;y<8;y++) if(y<x) offt += ((NB-1-y)>>3) + 1 - M9*NT;  // tail_y
    int ft = offt + (j - M9*NT);
    mt = 8*M9 + ft/NT;
    nt = ft - (ft/NT)*NT;
  }
}

// ---------------- cast x -> bf16 (vectorized) ----------------
__global__ void k_cvt_x(const float* __restrict__ x, unsigned short* __restrict__ xb){
  int i = blockIdx.x*256 + threadIdx.x;
  float4 v = ((const float4*)x)[i];
  ushort4 o; o.x=f2bf(v.x); o.y=f2bf(v.y); o.z=f2bf(v.z); o.w=f2bf(v.w);
  ((ushort4*)xb)[i] = o;
}

// ------------- transpose+cast weights: out[c][r] = bf16(in[r][c]) -------------
__global__ void k_transpose_cvt(const float* __restrict__ in, unsigned short* __restrict__ out,
                                int R, int CC){
  __shared__ float tile[64][65];
  int r0 = blockIdx.y*64, c0 = blockIdx.x*64;
  int tx = threadIdx.x & 63, ty = threadIdx.x >> 6;
  #pragma unroll
  for(int i=0;i<16;i++){
    int r = ty + i*4;
    tile[r][tx] = in[(size_t)(r0+r)*CC + c0 + tx];
  }
  __syncthreads();
  #pragma unroll
  for(int i=0;i<16;i++){
    int c = ty + i*4;
    out[(size_t)(c0+c)*R + r0 + tx] = f2bf(tile[tx][c]);
  }
}

// =================================================================================
// QKV GEMM (round 3): 128x128 tile, BK=64, 4 waves, DOUBLE-buffered LDS 64 KiB ->
// 2 blocks/CU co-residency. Rationale (r1/r2 post-mortem): at 256^2/8-phase with
// 1 block/CU, barrier lockstep serializes LDS-read phases against MFMA phases with
// nothing to overlap, and 333 blocks quantize to 2 generations (65%). Here the
// second resident block provides the overlap (m97/m114 mechanism) AND the load
// latency is covered by a full MFMA phase via counted vmcnt (never 0 mid-loop).
//   LDS units (16 KiB each): L[0]=A slot0, L[1]=A slot1, L[2]=B slot0, L[3]=B slot1
//   Schedule per k-tile g (slot s=g&1): READ 16 ds_read_b128 (tile g); lgkmcnt(0);
//   barrier; STAGE tile g+2 -> slot s (8 gld_lds); setprio MFMA x32; vmcnt(8)
//   [= tile g+1 complete, g+2 in flight]; barrier.
// T2 swizzle (kept from r2, conflict-free read mapping): element (row,kc) at
// ushort col kc ^ SWZ(row), SWZ(row)=((row&1)<<5)|(((row>>1)&3)<<3); LDS linear
// for global_load_lds, global source pre-XORed (same involution), reads XOR back.
// NOTE (r2 finding): SQ_LDS_BANK_CONFLICT ~3M is staging-write replay inherent to
// global_load_lds 16B mode (invariant across read swizzles) - not actionable.
// V-tiles (n0>=1536) written transposed into vtbuf (FUSEV), rest bf16 into qkvb.
// =================================================================================
__global__ __launch_bounds__(256,2) void k_gemm_qkv(const unsigned short* __restrict__ A,
                          const unsigned short* __restrict__ Bt,
                          unsigned short* __restrict__ qkvb,
                          unsigned short* __restrict__ vtbuf){
  __shared__ __align__(16) unsigned short L[4][8192];   // 64 KiB
  const int t = threadIdx.x;
  const int w = t>>6, l = t&63, lq = l>>4, lr = l&15;
  const int wm = w>>1, wn = w&1;                        // wave-tile 64x64
  int mt, nt; tile_map<18, 9, 73>(blockIdx.x, mt, nt);
  const int m0 = mt*128, n0 = nt*128;

  // staging: lane covers row rr=w*8+(l>>3) (+32*i), 16B chunk (l&7); source pre-swizzled
  const int rr = w*8 + (l>>3);
  const int csw = ((l&7)<<3) ^ ((((l>>3)&1)<<5) | (((l>>4)&3)<<3));
  const unsigned short* pA[4];
  const unsigned short* pB[4];
  #pragma unroll
  for(int i=0;i<4;i++){
    int ra = m0 + rr + 32*i; if(ra >= M_) ra = M_-1;   // +32 keeps row&7 -> same SWZ
    pA[i] = A  + (size_t)ra*768 + csw;
    pB[i] = Bt + (size_t)(n0 + rr + 32*i)*768 + csw;
  }
  // fragment-read swizzle: R_=base+16*f+lr => R_&1=lr&1, (R_>>1)&3=(lr>>1)&3
  const int fswz = ((lr&1)<<5) | (((lr>>1)&3)<<3);

#define STAGE(KT, SLT) do{ \
  unsigned short* dA_ = &L[(SLT)][w*512]; \
  unsigned short* dB_ = &L[2+(SLT)][w*512]; \
  _Pragma("unroll") \
  for(int i_=0;i_<4;i_++){ \
    gld_lds16(pA[i_] + (size_t)(KT)*64, dA_ + i_*2048); \
    gld_lds16(pB[i_] + (size_t)(KT)*64, dB_ + i_*2048); \
  } \
}while(0)
#define READ_ALL(S) do{ \
  const unsigned short* bA_ = &L[(S)][0]; \
  const unsigned short* bB_ = &L[2+(S)][0]; \
  _Pragma("unroll") \
  for(int mf=0;mf<4;mf++){ \
    const int R_ = wm*64 + mf*16 + lr; \
    af[mf][0] = *(const s16x8*)&bA_[R_*64 + ((lq*8) ^ fswz)]; \
    af[mf][1] = *(const s16x8*)&bA_[R_*64 + ((32 + lq*8) ^ fswz)]; \
  } \
  _Pragma("unroll") \
  for(int nf=0;nf<4;nf++){ \
    const int R_ = wn*64 + nf*16 + lr; \
    bf[nf][0] = *(const s16x8*)&bB_[R_*64 + ((lq*8) ^ fswz)]; \
    bf[nf][1] = *(const s16x8*)&bB_[R_*64 + ((32 + lq*8) ^ fswz)]; \
  } \
}while(0)
#define MMA_ALL() do{ \
  __builtin_amdgcn_s_setprio(1); \
  _Pragma("unroll") \
  for(int ks=0;ks<2;ks++) \
    _Pragma("unroll") \
    for(int mf=0;mf<4;mf++) \
      _Pragma("unroll") \
      for(int nf=0;nf<4;nf++) \
        acc[mf][nf] = __builtin_amdgcn_mfma_f32_16x16x32_bf16(af[mf][ks], bf[nf][ks], acc[mf][nf], 0,0,0); \
  __builtin_amdgcn_s_setprio(0); \
}while(0)

  f32x4 acc[4][4] = {};
  s16x8 af[4][2], bf[4][2];

  // prologue: stage tiles 0 and 1; wait tile 0 (oldest 8 of 16)
  STAGE(0, 0);
  STAGE(1, 1);
  asm volatile("s_waitcnt vmcnt(8)" ::: "memory");
  __builtin_amdgcn_s_barrier();

  for(int g=0; g<12; ++g){
    const int s = g&1;
    READ_ALL(s);
    asm volatile("s_waitcnt lgkmcnt(0)" ::: "memory");
    __builtin_amdgcn_sched_barrier(0);
    __builtin_amdgcn_s_barrier();          // all waves done reading slot s
    if(g<10){ STAGE(g+2, s); }             // overwrite the now-free slot
    MMA_ALL();
    if(g<10){
      asm volatile("s_waitcnt vmcnt(8)" ::: "memory");   // tile g+1 complete
    } else if(g==10){
      asm volatile("s_waitcnt vmcnt(0)" ::: "memory");   // drain tile 11
    }
    __builtin_amdgcn_s_barrier();          // everyone's tile g+1 loads visible
  }

  // ---- epilogue (r0 form): rows m0+wm*64+it*16+lq*4+r, cols n0+wn*64+jt*16+lr
  if(n0 >= 1536){
    // transposed V write: vtbuf[b*768 + (nc-1536)][token], 4 consecutive tokens/lane
    #pragma unroll
    for(int it=0;it<4;it++){
      int tok0 = m0 + wm*64 + it*16 + lq*4;
      #pragma unroll
      for(int jt=0;jt<4;jt++){
        int vrow = (n0 - 1536) + wn*64 + jt*16 + lr;
        ushort4 pk; unsigned short* pks = (unsigned short*)&pk;
        #pragma unroll
        for(int r=0;r<4;r++) pks[r] = f2bf(acc[it][jt][r]);
        int b0 = tok0/577, t0 = tok0 - b0*577;
        if(tok0 + 3 < M_ && t0 + 3 < 577){
          *(ushort4*)&vtbuf[(size_t)(b0*768 + vrow)*VTLD + t0] = pk;
        } else {
          #pragma unroll
          for(int r=0;r<4;r++){
            int tg = tok0 + r;
            if(tg < M_){
              int bb = tg/577, tt = tg - bb*577;
              vtbuf[(size_t)(bb*768 + vrow)*VTLD + tt] = pks[r];
            }
          }
        }
      }
    }
  } else {
    #pragma unroll
    for(int it=0;it<4;it++){
      #pragma unroll
      for(int r=0;r<4;r++){
        int row = m0 + wm*64 + it*16 + lq*4 + r;
        if(row < M_){
          #pragma unroll
          for(int jt=0;jt<4;jt++){
            int col = n0 + wn*64 + jt*16 + lr;
            qkvb[(size_t)row*2304 + col] = f2bf(acc[it][jt][r]);
          }
        }
      }
    }
  }
#undef STAGE
#undef READ_ALL
#undef MMA_ALL
}

// ---------------- bf16 MFMA GEMM, 64x128 tile (for parallelism-starved GEMM2) ----------------
// wave-tile 32x64 (acc 2x4 = 32 AGPR). f32 out + bias.
__global__ __launch_bounds__(256) void k_gemm_bt64(const unsigned short* __restrict__ A,
                          const unsigned short* __restrict__ Bt,
                          float* __restrict__ Cout,
                          const float* __restrict__ bias, int Mdim){
  __shared__ __align__(16) unsigned short As[64*32];    // 4 KB
  __shared__ __align__(16) unsigned short Bs[128*32];   // 8 KB
  const int t = threadIdx.x;
  const int w = t>>6, l = t&63, lq = l>>4, lr = l&15;
  const int wm = w>>1, wn = w&1;                        // wave-tile rows wm*32, cols wn*64
  int mt, nt; tile_map<6, 18, 145>(blockIdx.x, mt, nt);
  const int m0 = mt*64, n0 = nt*128;
  int rA0 = m0 + (t>>2);       if(rA0 >= Mdim) rA0 = Mdim-1;
  const unsigned short* gA0 = A  + (size_t)rA0*768 + (t&3)*8;
  const unsigned short* gB0 = Bt + (size_t)(n0 + (t>>2))*768 + (t&3)*8;
  const unsigned short* gB1 = Bt + (size_t)(n0 + ((t+256)>>2))*768 + (t&3)*8;
  unsigned short* lA0 = As + (size_t)w*512;
  unsigned short* lB0 = Bs + (size_t)w*512;
  unsigned short* lB1 = Bs + 2048 + (size_t)w*512;
  f32x4 acc[2][4] = {};
  for(int kt=0; kt<24; ++kt){
    const int ko = kt*32;
    __syncthreads();
    gld_lds16(gA0 + ko, lA0);
    gld_lds16(gB0 + ko, lB0); gld_lds16(gB1 + ko, lB1);
    __syncthreads();
    s16x8 af[2], bfr[4];
    #pragma unroll
    for(int it=0;it<2;it++) af[it]  = *(const s16x8*)&As[(wm*32+it*16+lr)*32 + lq*8];
    #pragma unroll
    for(int jt=0;jt<4;jt++) bfr[jt] = *(const s16x8*)&Bs[(wn*64+jt*16+lr)*32 + lq*8];
    #pragma unroll
    for(int it=0;it<2;it++)
      #pragma unroll
      for(int jt=0;jt<4;jt++)
        acc[it][jt] = __builtin_amdgcn_mfma_f32_16x16x32_bf16(af[it], bfr[jt], acc[it][jt], 0,0,0);
  }
  #pragma unroll
  for(int it=0;it<2;it++){
    #pragma unroll
    for(int r=0;r<4;r++){
      int row = m0 + wm*32 + it*16 + lq*4 + r;
      if(row < Mdim){
        #pragma unroll
        for(int jt=0;jt<4;jt++){
          int col = n0 + wn*64 + jt*16 + lr;
          Cout[(size_t)row*768 + col] = acc[it][jt][r] + bias[col];
        }
      }
    }
  }
}

// ---------------- fused flash attention, max-free softmax, S^T, peeled edge tile ----------------
__global__ __launch_bounds__(256,4) void k_attn(const unsigned short* __restrict__ qkv,
                                                const unsigned short* __restrict__ vtbuf,
                                                unsigned short* __restrict__ aout){
  __shared__ __align__(16) unsigned short Ks[64*64];
  __shared__ __align__(16) unsigned short Vt[64*64];
  __shared__ __align__(16) unsigned short Ptt[128*PTLD];
  __shared__ float Ls[4][2][16][4];
  const int blk = blockIdx.x;
  const int bh = blk % 192, qt = blk / 192;
  const int b = bh / 12, h = bh % 12;
  const int t = threadIdx.x, w = t>>6, l = t&63, lq = l>>4, lr = l&15;
  const size_t base = (size_t)(b*577)*2304 + h*64;
  const int q0 = qt*128;
  s16x8 bq[2][2];
  #pragma unroll
  for(int it=0;it<2;it++){
    int qrow = q0 + w*32 + it*16 + lr; if(qrow > 576) qrow = 576;
    #pragma unroll
    for(int ks=0;ks<2;ks++)
      bq[it][ks] = *(const s16x8*)&qkv[base + (size_t)qrow*2304 + ks*32 + lq*8];
  }
  const int srow = w*8 + (l>>3);
  const int cswz8 = (((l&7) ^ (l>>3)) << 3);
  unsigned short* ldsK = Ks + (size_t)w*512;
  unsigned short* ldsV = Vt + (size_t)w*512;
  const unsigned short* gVbase = vtbuf + (size_t)(bh*64)*VTLD + cswz8;

  f32x4 acc_o[2][4] = {};
  float lsum[2] = {0.f, 0.f};
  const float CEXP = 0.18033688011112043f;              // 0.125 * log2(e)

  auto tile_body = [&](int j0, bool edge){
    __syncthreads();
    #pragma unroll
    for(int i=0;i<2;i++){
      int krow = j0 + i*32 + srow; if(krow > 576) krow = 576;
      gld_lds16(qkv + base + 768 + (size_t)krow*2304 + cswz8, ldsK + i*2048);
      gld_lds16(gVbase + (size_t)(i*32 + srow)*VTLD + j0,     ldsV + i*2048);
    }
    __syncthreads();
    f32x4 accs[2][4] = {};
    #pragma unroll
    for(int ks=0;ks<2;ks++){
      s16x8 ak[4];
      #pragma unroll
      for(int jt=0;jt<4;jt++){
        int j = jt*16 + lr;
        ak[jt] = *(const s16x8*)&Ks[j*64 + (((4*ks+lq) ^ (j&7))<<3)];
      }
      #pragma unroll
      for(int it=0;it<2;it++)
        #pragma unroll
        for(int jt=0;jt<4;jt++)
          accs[it][jt] = __builtin_amdgcn_mfma_f32_16x16x32_bf16(ak[jt], bq[it][ks], accs[it][jt], 0,0,0);
    }
    #pragma unroll
    for(int it=0;it<2;it++){
      int qlocal = w*32 + it*16 + lr;
      #pragma unroll
      for(int jt=0;jt<4;jt++){
        ushort4 pk;
        unsigned short* pks = (unsigned short*)&pk;
        #pragma unroll
        for(int r=0;r<4;r++){
          float p = exp2f(accs[it][jt][r] * CEXP);
          if(edge){ if(j0 + jt*16 + lq*4 + r > 576) p = 0.f; }
          lsum[it] += p;
          pks[r] = f2bf(p);
        }
        *(ushort4*)&Ptt[qlocal*PTLD + jt*16 + lq*4] = pk;
      }
    }
    #pragma unroll
    for(int ks=0;ks<2;ks++){
      s16x8 ap[2], bv[4];
      #pragma unroll
      for(int it=0;it<2;it++)
        ap[it] = *(const s16x8*)&Ptt[(w*32+it*16+lr)*PTLD + ks*32 + lq*8];
      #pragma unroll
      for(int dt=0;dt<4;dt++){
        int d = dt*16 + lr;
        bv[dt] = *(const s16x8*)&Vt[d*64 + (((4*ks+lq) ^ (d&7))<<3)];
      }
      #pragma unroll
      for(int it=0;it<2;it++)
        #pragma unroll
        for(int dt=0;dt<4;dt++)
          acc_o[it][dt] = __builtin_amdgcn_mfma_f32_16x16x32_bf16(ap[it], bv[dt], acc_o[it][dt], 0,0,0);
    }
  };
  for(int j0=0; j0<576; j0+=64) tile_body(j0, false);   // j <= 575: no masking needed
  tile_body(576, true);                                 // edge tile: only j=576 valid

  #pragma unroll
  for(int it=0;it<2;it++) Ls[w][it][lr][lq] = lsum[it];
  #pragma unroll
  for(int it=0;it<2;it++){
    #pragma unroll
    for(int r=0;r<4;r++){
      int n = q0 + w*32 + it*16 + lq*4 + r;
      if(n <= 576){
        int q16 = lq*4 + r;
        float lt = Ls[w][it][q16][0] + Ls[w][it][q16][1] + Ls[w][it][q16][2] + Ls[w][it][q16][3];
        float inv = 1.f / lt;
        #pragma unroll
        for(int dt=0;dt<4;dt++)
          aout[(size_t)(b*577+n)*768 + h*64 + dt*16 + lr] = f2bf(acc_o[it][dt][r]*inv);
      }
    }
  }
}

// ---------------- fp32 top-k path (exact ranking) ----------------
__global__ void k_qcls(const float* __restrict__ x, const float* __restrict__ Wqkv,
                       float* __restrict__ qcls){
  __shared__ float xs[768];
  __shared__ float part[4][64];
  const int b = blockIdx.y, j0 = blockIdx.x*64;
  const int t = threadIdx.x;
  const float* xr = x + (size_t)b*577*768;
  xs[t] = xr[t]; xs[t+256] = xr[t+256]; xs[t+512] = xr[t+512];
  __syncthreads();
  const int jl = t & 63, cs = t >> 6;
  float acc = 0.f;
  const float* wp = Wqkv + (size_t)(cs*192)*2304 + j0 + jl;
  #pragma unroll 4
  for(int c=0;c<192;c++){ acc += xs[cs*192+c] * wp[0]; wp += 2304; }
  part[cs][jl] = acc;
  __syncthreads();
  if(t < 64) qcls[b*768 + j0 + t] = part[0][t]+part[1][t]+part[2][t]+part[3][t];
}
__global__ void k_u(const float* __restrict__ Wqkv, const float* __restrict__ qcls,
                    float* __restrict__ u){
  int h = blockIdx.x, b = blockIdx.y, c = threadIdx.x;  // 768 threads
  const float* qc = qcls + b*768 + h*64;
  const float* wr = Wqkv + (size_t)c*2304 + 768 + h*64;
  float acc = 0.f;
  #pragma unroll
  for(int d=0;d<64;d++) acc += wr[d]*qc[d];
  u[(size_t)(b*12+h)*768 + c] = acc;
}
__global__ void k_attw(const float* __restrict__ x, const float* __restrict__ u,
                       float* __restrict__ attw){
  int blk = blockIdx.x;               // 16*577 blocks of 1 wave
  int b = blk/577, m = blk%577;
  int lane = threadIdx.x;
  const float* xr = x + (size_t)(b*577+m)*768;
  const float* ub = u + (size_t)b*12*768;
  float part[12];
  #pragma unroll
  for(int h=0;h<12;h++) part[h]=0.f;
  #pragma unroll
  for(int i=0;i<12;i++){
    float xv = xr[i*64 + lane];
    #pragma unroll
    for(int h=0;h<12;h++) part[h] += xv * ub[h*768 + i*64 + lane];
  }
  float s = 0.f;
  #pragma unroll
  for(int h=0;h<12;h++){
    float v = part[h];
    #pragma unroll
    for(int off=32; off; off>>=1) v += __shfl_xor(v, off);
    s += fabsf(v);
  }
  if(lane==0) attw[b*577 + m] = 0.125f * s;
}
__global__ void k_topk(const float* __restrict__ attw, int* __restrict__ idxbuf){
  __shared__ float sw[576];
  __shared__ int wtot[9];
  int b = blockIdx.x, t = threadIdx.x;     // 576 threads
  float wv = attw[b*577 + 1 + t];
  sw[t] = wv;
  __syncthreads();
  int rank = 0;
  for(int j=0;j<576;j++){
    float wj = sw[j];
    rank += (wj > wv) || (wj == wv && j < t);
  }
  bool kept = rank < NKEEP;
  unsigned long long mask = __ballot(kept);
  int wid = t>>6, lane = t&63;
  int pos = __popcll(mask & ((1ull<<lane)-1ull));
  if(lane==0) wtot[wid] = __popcll(mask);
  __syncthreads();
  int off0 = 0;
  for(int q=0;q<wid;q++) off0 += wtot[q];
  if(kept) idxbuf[b*KROWS + 1 + off0 + pos] = t+1;
  if(t==0) idxbuf[b*KROWS] = 0;
}
__global__ void k_fill_keep(const int* __restrict__ idxbuf, float* __restrict__ out2){
  int i4 = blockIdx.x*256 + threadIdx.x;
  float v = (float)idxbuf[i4/192];
  ((float4*)out2)[i4] = make_float4(v,v,v,v);
}

extern "C" void kernel_launch(void* const* d_in, const int* in_sizes, int n_in,
                              void* d_out, int out_size, void* d_ws, size_t ws_size,
                              hipStream_t stream){
  const float* x     = (const float*)d_in[0];
  const float* Wqkv  = (const float*)d_in[1];
  const float* Wproj = (const float*)d_in[2];
  const float* bias  = (const float*)d_in[3];
  float* out  = (float*)d_out;
  float* out2 = out + (size_t)M_*768;      // keep_index chunk (float32)

  char* ws = (char*)d_ws;
  size_t off = 0;
  auto alloc = [&](size_t bytes)->void*{ void* p = ws + off; off += (bytes + 255) & ~(size_t)255; return p; };
  unsigned short* xb     = (unsigned short*)alloc((size_t)M_*768*2);
  unsigned short* wqkvT  = (unsigned short*)alloc((size_t)QKVN*768*2);
  unsigned short* wprojT = (unsigned short*)alloc((size_t)768*768*2);
  unsigned short* qkvb   = (unsigned short*)alloc((size_t)M_*QKVN*2);
  unsigned short* aoutb  = (unsigned short*)alloc((size_t)M_*768*2);
  unsigned short* vtbuf  = (unsigned short*)alloc((size_t)192*64*VTLD*2);
  float* qcls   = (float*)alloc((size_t)16*768*4);
  float* u      = (float*)alloc((size_t)16*12*768*4);
  float* attw   = (float*)alloc((size_t)16*577*4);
  int*   idxbuf = (int*)alloc((size_t)16*KROWS*4);

  // bf16 casts / transposes
  k_cvt_x<<<6924, 256, 0, stream>>>(x, xb);
  k_transpose_cvt<<<dim3(36,12), 256, 0, stream>>>(Wqkv,  wqkvT, 768, 2304);
  k_transpose_cvt<<<dim3(12,12), 256, 0, stream>>>(Wproj, wprojT, 768, 768);
  // QKV GEMM (bf16 out; V-tiles written transposed into vtbuf). 128^2 dbuf, 2 blk/CU.
  k_gemm_qkv<<<73*18, 256, 0, stream>>>(xb, wqkvT, qkvb, vtbuf);
  // fp32 top-k weight path
  k_qcls<<<dim3(12,16), 256, 0, stream>>>(x, Wqkv, qcls);
  k_u<<<dim3(12,16), 768, 0, stream>>>(Wqkv, qcls, u);
  k_attw<<<16*577, 64, 0, stream>>>(x, u, attw);
  k_topk<<<16, 576, 0, stream>>>(attw, idxbuf);
  k_fill_keep<<<(16*KROWS*768/4 + 255)/256, 256, 0, stream>>>(idxbuf, out2);
  // attention + out-proj
  k_attn<<<960, 256, 0, stream>>>(qkvb, vtbuf, aoutb);
  k_gemm_bt64<<<145*6, 256, 0, stream>>>(aoutb, wprojT, out, bias, M_);
}